// Round 10
// baseline (2225.202 us; speedup 1.0000x reference)
//
#include <hip/hip_runtime.h>
#include <stdint.h>

typedef unsigned short ushort_t;
typedef __attribute__((ext_vector_type(8))) short short8;
typedef __attribute__((ext_vector_type(4))) float float4v;
typedef __attribute__((ext_vector_type(4))) int int4v;

#define TSTEPS 512
#define NBATCH 128
#define HID 256
#define NIN 64
#define RB 32           // ring depth (steps); gen bit flips every RB steps
#define NBHID (NBATCH*HID)
#define RING_DW (RB*NBHID)

// workspace layout (bytes) — rings: u32 per element = (lo_bf16<<16) | tagged_hi
// SAFE rings (sc0 sc1, IC-coherent) + FAST rings (sc0, per-XCD L2) back-to-back.
#define OFF_FLAGS   0u                             // 4096 padded ints = 16KB
#define OFF_BIAS    16384u
#define OFF_H1R     32768u
#define RING_BYTES  (RB*(unsigned)NBATCH*HID*4u)   // 4,194,304 per ring
#define OFF_H2R     (OFF_H1R + RING_BYTES)
#define OFF_H1F     (OFF_H2R + RING_BYTES)
#define OFF_H2F     (OFF_H1F + RING_BYTES)
#define OFF_WF1     (OFF_H2F + RING_BYTES)
#define WF1_FRAGS   (16*8*4*4)                     // 2048 fragments of 1KB
#define OFF_WF2     (OFF_WF1 + WF1_FRAGS*1024u)
#define WF2_FRAGS   (16*8*6*4)                     // 3072
#define OFF_HOUT    (OFF_WF2 + WF2_FRAGS*1024u)    // 128*256 fp32 = 128KB

// flags[] int layout: [0,3072) protocol/progress (stride-16 padded),
// [3072,3328) = per-block XCC table (prefilled -1).

// Handoff = R9 (verified correct, absmax 0.0) + DYNAMIC XCD group formation:
//  - one-time prologue: every WG publishes its XCC_ID (hwreg 20) through IC,
//    polls all 256 entries (co-resident cooperative launch -> bounded), then
//    deterministically computes identical group assignments: first 32 WGs on
//    XCD c = group c (roles 0-31); overflow WGs fill vacancies of under-full
//    groups; any group with a foreign member runs IC-scope.
//  - fast groups (all-local): sentinel polls + stage loads on the FAST ring
//    (sc0 -> shared XCD L2), bounded retries, sticky per-WG fallback to the
//    SAFE ring (sc0 sc1) -> hang-proof regardless of sc0 semantics.
//  - producers always dual-store (FAST sc0 + SAFE sc0 sc1), NO drain, NO flag.
//  - numerics: tagged hi (LSB=gen), lo computed vs tagged hi at full RNE
//    (absmax 0.0, verified R4/R8/R9). Rings prefilled 0x00000001.

__device__ __forceinline__ ushort_t bf16h(float f) {
    unsigned u = __float_as_uint(f);
    u += 0x7fffu + ((u >> 16) & 1u);
    return (ushort_t)(u >> 16);
}
__device__ __forceinline__ float bf16f(ushort_t h) {
    return __uint_as_float(((unsigned)h) << 16);
}
__device__ __forceinline__ unsigned genbit(int s) {   // valid for s >= -64
    return ((unsigned)(s + 64) >> 5) & 1u;
}

// ---- scope-templated access helpers. SYS=true: sc0 sc1 (IC, device-coherent).
// SYS=false: sc0 (bypass L1; served by the XCD's shared L2). ----

template<bool SYS>
__device__ __forceinline__ int ld_i32(const void* p) {
    int r;
    if constexpr (SYS)
        asm volatile("global_load_dword %0, %1, off sc0 sc1\n\ts_waitcnt vmcnt(0)"
                     : "=v"(r) : "v"(p) : "memory");
    else
        asm volatile("global_load_dword %0, %1, off sc0\n\ts_waitcnt vmcnt(0)"
                     : "=v"(r) : "v"(p) : "memory");
    return r;
}
__device__ __forceinline__ float ld_cg_f32(const void* p) {
    float r;
    asm volatile("global_load_dword %0, %1, off sc0 sc1\n\ts_waitcnt vmcnt(0)"
                 : "=v"(r) : "v"(p) : "memory");
    return r;
}
template<bool SYS>
__device__ __forceinline__ void ld2x4(int4v& a, int4v& b, const void* p) {
    if constexpr (SYS)
        asm volatile("global_load_dwordx4 %0, %2, off sc0 sc1\n\t"
                     "global_load_dwordx4 %1, %2, off offset:16 sc0 sc1\n\t"
                     "s_waitcnt vmcnt(0)"
                     : "=&v"(a), "=&v"(b) : "v"(p) : "memory");
    else
        asm volatile("global_load_dwordx4 %0, %2, off sc0\n\t"
                     "global_load_dwordx4 %1, %2, off offset:16 sc0\n\t"
                     "s_waitcnt vmcnt(0)"
                     : "=&v"(a), "=&v"(b) : "v"(p) : "memory");
}
template<bool SYS>
__device__ __forceinline__ void ld4x4(int4v& a, int4v& b, int4v& c, int4v& d,
                                      const void* p, const void* q) {
    if constexpr (SYS)
        asm volatile("global_load_dwordx4 %0, %4, off sc0 sc1\n\t"
                     "global_load_dwordx4 %1, %4, off offset:16 sc0 sc1\n\t"
                     "global_load_dwordx4 %2, %5, off sc0 sc1\n\t"
                     "global_load_dwordx4 %3, %5, off offset:16 sc0 sc1\n\t"
                     "s_waitcnt vmcnt(0)"
                     : "=&v"(a), "=&v"(b), "=&v"(c), "=&v"(d)
                     : "v"(p), "v"(q) : "memory");
    else
        asm volatile("global_load_dwordx4 %0, %4, off sc0\n\t"
                     "global_load_dwordx4 %1, %4, off offset:16 sc0\n\t"
                     "global_load_dwordx4 %2, %5, off sc0\n\t"
                     "global_load_dwordx4 %3, %5, off offset:16 sc0\n\t"
                     "s_waitcnt vmcnt(0)"
                     : "=&v"(a), "=&v"(b), "=&v"(c), "=&v"(d)
                     : "v"(p), "v"(q) : "memory");
}
__device__ __forceinline__ void st_u32_fast(void* p, unsigned v) {
    asm volatile("global_store_dword %0, %1, off sc0" :: "v"(p), "v"(v) : "memory");
}
__device__ __forceinline__ void st_u32_safe(void* p, unsigned v) {
    asm volatile("global_store_dword %0, %1, off sc0 sc1" :: "v"(p), "v"(v) : "memory");
}
__device__ __forceinline__ void st_cg_i32(int* p, int v) {
    asm volatile("global_store_dword %0, %1, off sc0 sc1" :: "v"(p), "v"(v) : "memory");
}
__device__ __forceinline__ void st_cg_f32(void* p, float v) {
    asm volatile("global_store_dword %0, %1, off sc0 sc1" :: "v"(p), "v"(v) : "memory");
}

// all 8 u32 LSBs (the hi-plane tags) equal gw (0 or 1)?
__device__ __forceinline__ bool tag8(int4v a, int4v b, unsigned gw) {
    unsigned x = ((unsigned)a[0] ^ gw) | ((unsigned)a[1] ^ gw) |
                 ((unsigned)a[2] ^ gw) | ((unsigned)a[3] ^ gw) |
                 ((unsigned)b[0] ^ gw) | ((unsigned)b[1] ^ gw) |
                 ((unsigned)b[2] ^ gw) | ((unsigned)b[3] ^ gw);
    return (x & 1u) == 0u;
}

// extract 8 low u16 (hi plane) / 8 high u16 (lo plane) from 8 packed u32
__device__ __forceinline__ int4v ext_hi8(int4v a, int4v b) {
    int4v r;
    r[0] = (int)__builtin_amdgcn_perm((unsigned)a[1], (unsigned)a[0], 0x05040100u);
    r[1] = (int)__builtin_amdgcn_perm((unsigned)a[3], (unsigned)a[2], 0x05040100u);
    r[2] = (int)__builtin_amdgcn_perm((unsigned)b[1], (unsigned)b[0], 0x05040100u);
    r[3] = (int)__builtin_amdgcn_perm((unsigned)b[3], (unsigned)b[2], 0x05040100u);
    return r;
}
__device__ __forceinline__ int4v ext_lo8(int4v a, int4v b) {
    int4v r;
    r[0] = (int)__builtin_amdgcn_perm((unsigned)a[1], (unsigned)a[0], 0x07060302u);
    r[1] = (int)__builtin_amdgcn_perm((unsigned)a[3], (unsigned)a[2], 0x07060302u);
    r[2] = (int)__builtin_amdgcn_perm((unsigned)b[1], (unsigned)b[0], 0x07060302u);
    r[3] = (int)__builtin_amdgcn_perm((unsigned)b[3], (unsigned)b[2], 0x07060302u);
    return r;
}

// ---------------- prep kernels ----------------

__global__ void prep_misc(const float* bxh1, const float* bhh1,
                          const float* bxh2, const float* bhh2,
                          float* bias, int* flags, unsigned* ring_all)
{
    int n = blockIdx.x * blockDim.x + threadIdx.x;
    if (n < 1024)       bias[n] = bxh1[n] + bhh1[n];
    else if (n < 2048)  bias[n] = bxh2[n - 1024] + bhh2[n - 1024];
    else if (n < 6144)  {
        int i = n - 2048;
        flags[i] = (i >= 3072 && i < 3328) ? -1 : 0;   // XCC table = -1
    } else {
        unsigned d = n - 6144;
        if (d < 4u * RING_DW)                        // safe + fast rings
            ring_all[d] = 0x00000001u;   // tag = gen(-1) = 1, value ~ 0
    }
}

// Build MFMA B-fragments (hi/lo split weights) in exact consumption order:
// fragment id = ((slice*8 + wave)*F + i)*4 + ntile ; each fragment = [lane][8] bf16.
__global__ void prep_wf(const float* Wxh1, const float* Whh1,
                        const float* Wxh2, const float* Whh2,
                        ushort_t* wf1, ushort_t* wf2)
{
    int n = blockIdx.x * blockDim.x + threadIdx.x;
    const int L1E = WF1_FRAGS * 512;
    const int L2E = WF2_FRAGS * 512;
    if (n >= L1E + L2E) return;
    int layer = (n >= L1E) ? 1 : 0;
    int e = layer ? (n - L1E) : n;
    int el = e & 511;
    int f  = e >> 9;
    int lane = el >> 3, j = el & 7;
    int nt = f & 3;
    int rem = f >> 2;
    int i, wv, slice, F, S;
    if (!layer) { F = 4; S = 10; i = rem & 3; wv = (rem >> 2) & 7; slice = rem >> 5; }
    else        { F = 6; S = 16; i = rem % 6; int r2 = rem / 6; wv = r2 & 7; slice = r2 >> 3; }
    int fg = wv * F + i;
    int col = lane & 15;
    int row = nt * 256 + slice * 16 + col;
    float val = 0.f;
    if (fg < 3 * S) {
        int sec = (fg < S) ? 0 : ((fg < 2 * S) ? 1 : 2);
        int ks = (fg - sec * S) * 32 + (lane >> 4) * 8 + j;
        float w;
        if (!layer) w = (ks < 256) ? Whh1[row * 256 + ks] : Wxh1[row * 64 + (ks - 256)];
        else        w = (ks < 256) ? Wxh2[row * 256 + ks] : Whh2[row * 256 + (ks - 256)];
        ushort_t hi = bf16h(w);
        val = (sec < 2) ? bf16f(hi) : (w - bf16f(hi));
    }
    (layer ? wf2 : wf1)[e] = bf16h(val);
}

// ---------------- recurrent kernel ----------------

template<int LAYER, int F, int S, int PITCH>
__device__ __forceinline__ void run_layer(
    int g, int slice, int tid, int fastInit, const float* __restrict__ x,
    int* flags, const float* bias,
    unsigned* h1r, unsigned* h2r, unsigned* h1f, unsigned* h2f,
    const ushort_t* wfrag, float* hOut,
    ushort_t* sA, ushort_t* sB, float (*red)[4][64][4], int* fastMode)
{
    const int wv = tid >> 6, lane = tid & 63;
    const int mrow = lane & 15, q = lane >> 4;
    int* f1 = flags + g * 256;                    // layer1 progress (stride 16)
    int* f2 = flags + 2048 + g * 256;             // layer2 progress
    int* myflag = flags + LAYER * 2048 + g * 256 + slice * 16;

    // persistent B fragments in VGPRs
    short8 bw[4][F];
    {
        const ushort_t* base = wfrag + (size_t)((slice * 8 + wv) * F) * 4 * 512;
        #pragma unroll
        for (int i = 0; i < F; i++)
            #pragma unroll
            for (int nt = 0; nt < 4; nt++)
                bw[nt][i] = *(const short8*)(base + (i * 4 + nt) * 512 + lane * 8);
    }

    float bs[4];
    #pragma unroll
    for (int nt = 0; nt < 4; nt++)
        bs[nt] = bias[LAYER * 1024 + nt * 256 + slice * 16 + mrow];

    float cst[4] = {0,0,0,0}, mst[4] = {0,0,0,0}, nst[4] = {0,0,0,0};

    const int sr = tid >> 5, k = tid & 31;  // staging: row sr, element chunk k*8
    const int row = g * 16 + sr;

    if (tid == 0) *fastMode = fastInit;
    __syncthreads();

    for (int t = 0; t < TSTEPS; t++) {
        // ---- x staging (layer1, waves 2-3; plain cached loads) ----
        if (LAYER == 0 && tid >= 128 && tid < 256) {
            int idx = tid - 128;          // 0..127
            int r = idx >> 3, o = idx & 7;
            const float* xsrc = x + ((size_t)(g * 16 + r) * TSTEPS + t) * NIN + o * 8;
            float4v x0 = *(const float4v*)xsrc;
            float4v x1 = *(const float4v*)(xsrc + 4);
            float xs[8] = {x0[0], x0[1], x0[2], x0[3], x1[0], x1[1], x1[2], x1[3]};
            union { ushort_t u[8]; int4v v4; } hiP, loP;
            #pragma unroll
            for (int z = 0; z < 8; z++) {
                ushort_t hi = bf16h(xs[z]);
                hiP.u[z] = hi;
                loP.u[z] = bf16h(xs[z] - bf16f(hi));
            }
            *(int4v*)(sA + r * PITCH + (32 + o) * 8) = hiP.v4;
            *(int4v*)(sB + r * PITCH + (32 + o) * 8) = loP.v4;
        }

        // ---- wave1: sentinel discovery (fast, bounded -> safe) + backpressure ----
        if (tid >= 64 && tid < 128) {
            int pl = tid - 64;
            const unsigned *spF = nullptr, *spS = nullptr;
            unsigned want = 0;
            if (LAYER == 0) {
                if (pl < 16) {
                    size_t off = (size_t)((t - 1) & (RB - 1)) * NBHID
                               + (size_t)(g * 16 + 15) * HID + pl * 16 + 15;
                    spF = h1f + off; spS = h1r + off; want = genbit(t - 1);
                }
            } else {
                if (pl < 16) {
                    size_t off = (size_t)(t & (RB - 1)) * NBHID
                               + (size_t)(g * 16 + 15) * HID + pl * 16 + 15;
                    spF = h1f + off; spS = h1r + off; want = genbit(t);
                } else if (pl < 32) {
                    size_t off = (size_t)((t - 1) & (RB - 1)) * NBHID
                               + (size_t)(g * 16 + 15) * HID + (pl - 16) * 16 + 15;
                    spF = h2f + off; spS = h2r + off; want = genbit(t - 1);
                }
            }
            if (spF) {
                if (*fastMode) {
                    bool ok = false;
                    for (int it = 0; it < 256; it++) {
                        if ((((unsigned)ld_i32<false>(spF)) & 1u) == want) { ok = true; break; }
                    }
                    if (!ok) {
                        *fastMode = 0;   // sticky fallback (benign LDS race)
                        while ((((unsigned)ld_i32<true>(spS)) & 1u) != want) { }
                    }
                } else {
                    while ((((unsigned)ld_i32<true>(spS)) & 1u) != want) { }
                }
            } else if (pl >= 32 && (t & 7) == 0) {
                // lazy ring backpressure: consumers' staged progress >= t-22
                int thr = t - 22;
                const int* p = nullptr;
                if (LAYER == 0) {
                    if (pl < 48)      p = f1 + (pl - 32) * 16;
                    else              p = f2 + (pl - 48) * 16;
                } else {
                    if (pl < 48)      p = f2 + (pl - 32) * 16;
                }
                if (p)
                    while (ld_i32<true>(p) < thr) { }
            }
        }
        __syncthreads();

        // ---- cooperative tag-validated stage (fast, bounded -> safe) ----
        {
            const bool fm = (*fastMode != 0);
            if (LAYER == 0) {
                size_t off = ((size_t)((t - 1) & (RB - 1)) * NBATCH + row) * HID + k * 8;
                unsigned w = genbit(t - 1);
                int4v a, b;
                bool ok = false;
                if (fm) {
                    for (int it = 0; it < 32; it++) {
                        ld2x4<false>(a, b, h1f + off);
                        if (tag8(a, b, w)) { ok = true; break; }
                    }
                }
                if (!ok) {
                    if (fm) *fastMode = 0;
                    do { ld2x4<true>(a, b, h1r + off); } while (!tag8(a, b, w));
                }
                *(int4v*)(sA + sr * PITCH + k * 8) = ext_hi8(a, b);
                *(int4v*)(sB + sr * PITCH + k * 8) = ext_lo8(a, b);
            } else {
                size_t off1 = ((size_t)(t & (RB - 1)) * NBATCH + row) * HID + k * 8;
                size_t off2 = ((size_t)((t - 1) & (RB - 1)) * NBATCH + row) * HID + k * 8;
                unsigned w1 = genbit(t), w2 = genbit(t - 1);
                int4v a, b, c, d;
                bool ok = false;
                if (fm) {
                    for (int it = 0; it < 32; it++) {
                        ld4x4<false>(a, b, c, d, h1f + off1, h2f + off2);
                        if (tag8(a, b, w1) && tag8(c, d, w2)) { ok = true; break; }
                    }
                }
                if (!ok) {
                    if (fm) *fastMode = 0;
                    do { ld4x4<true>(a, b, c, d, h1r + off1, h2r + off2); }
                    while (!(tag8(a, b, w1) && tag8(c, d, w2)));
                }
                *(int4v*)(sA + sr * PITCH + k * 8)        = ext_hi8(a, b);
                *(int4v*)(sB + sr * PITCH + k * 8)        = ext_lo8(a, b);
                *(int4v*)(sA + sr * PITCH + (32 + k) * 8) = ext_hi8(c, d);
                *(int4v*)(sB + sr * PITCH + (32 + k) * 8) = ext_lo8(c, d);
            }
        }
        __syncthreads();

        // ---- progress publish (lazy backpressure input; off critical path) ----
        if (tid == 256 && (t & 7) == 0)
            st_cg_i32(myflag, t);

        // ---- MFMA: this wave's K-chunks across the 4 gate N-tiles ----
        float4v acc[4] = {};
        #pragma unroll
        for (int i = 0; i < F; i++) {
            const int fg = wv * F + i;
            short8 a;
            if (fg < 3 * S) {
                int sec = (fg >= S && fg < 2 * S) ? 1 : 0;
                int ks = ((fg < S) ? fg : ((fg < 2 * S) ? fg - S : fg - 2 * S)) * 32;
                const ushort_t* ap = (sec ? sB : sA) + mrow * PITCH + ks + q * 8;
                a = *(const short8*)ap;
            } else {
                a = (short8){0,0,0,0,0,0,0,0};
            }
            #pragma unroll
            for (int nt = 0; nt < 4; nt++)
                acc[nt] = __builtin_amdgcn_mfma_f32_16x16x32_bf16(a, bw[nt][i], acc[nt], 0, 0, 0);
        }

        // ---- flat reduction: waves 1-7 dump once, wave0 sums 7 ----
        if (wv != 0) {
            #pragma unroll
            for (int nt = 0; nt < 4; nt++) *(float4v*)red[wv - 1][nt][lane] = acc[nt];
        }
        __syncthreads();

        // ---- wave0: sum + cell + dual tagged stores (NO drain, NO flag) ----
        if (wv == 0) {
            #pragma unroll
            for (int w = 0; w < 7; w++)
                #pragma unroll
                for (int nt = 0; nt < 4; nt++)
                    acc[nt] += *(const float4v*)red[w][nt][lane];

            unsigned* baseS = (LAYER ? h2r : h1r) + (size_t)(t & (RB - 1)) * NBHID;
            unsigned* baseF = (LAYER ? h2f : h1f) + (size_t)(t & (RB - 1)) * NBHID;
            unsigned gw = genbit(t);
            #pragma unroll
            for (int r2 = 0; r2 < 4; r2++) {
                float ig  = acc[0][r2] + bs[0];
                float fgt = acc[1][r2] + bs[1];
                float zg  = acc[2][r2] + bs[2];
                float og  = acc[3][r2] + bs[3];
                float zc = fminf(fmaxf(zg, -15.f), 15.f);
                float e2 = __expf(2.f * zc);
                float zt = (e2 - 1.f) / (e2 + 1.f);
                float ot = 1.f / (1.f + __expf(-og));
                float mt = fmaxf(fgt + mst[r2], ig);
                float it = __expf(ig - mt);
                float ft = __expf(fgt + mst[r2] - mt);
                cst[r2] = ft * cst[r2] + it * zt;
                nst[r2] = ft * nst[r2] + it;
                mst[r2] = mt;
                float h = ot * (cst[r2] / nst[r2]);
                ushort_t hi = (ushort_t)(((unsigned)bf16h(h) & 0xFFFEu) | gw);
                float rem = h - bf16f(hi);
                ushort_t lo = bf16h(rem);
                unsigned word = ((unsigned)lo << 16) | (unsigned)hi;
                int orow = g * 16 + q * 4 + r2;
                int col = slice * 16 + mrow;
                size_t idx = (size_t)orow * HID + col;
                st_u32_fast(baseF + idx, word);
                st_u32_safe(baseS + idx, word);
                if (LAYER == 1 && t == TSTEPS - 1)
                    st_cg_f32(hOut + idx, h);
            }
            // lane63's r2=3 word (row g*16+15, col slice*16+15) is the sentinel.
        }
    }
}

__global__ __launch_bounds__(512, 2) void recur(
    const float* __restrict__ x,
    int* flags, const float* bias,
    unsigned* h1r, unsigned* h2r, unsigned* h1f, unsigned* h2f,
    const ushort_t* wf1, const ushort_t* wf2, float* hOut)
{
    __shared__ alignas(16) ushort_t sA[16 * 520];
    __shared__ alignas(16) ushort_t sB[16 * 520];
    __shared__ float red[7][4][64][4];
    __shared__ int fastMode;
    __shared__ int xsTab[256];
    __shared__ int asn[3];

    // ---- one-time dynamic XCD group formation ----
    int* xccTab = flags + 3072;
    if (threadIdx.x == 0) {
        // hwreg 20 = HW_REG_XCC_ID (gfx940+); imm = ((32-1)<<11)|(0<<6)|20
        unsigned xcc = (unsigned)__builtin_amdgcn_s_getreg(63508);
        st_cg_i32(xccTab + blockIdx.x, (int)(xcc & 7u));
    }
    if (threadIdx.x < 256) {
        int v;
        do { v = ld_i32<true>(xccTab + threadIdx.x); } while (v == -1);
        xsTab[threadIdx.x] = v;
    }
    __syncthreads();
    if (threadIdx.x == 0) {
        int cnt[8] = {0,0,0,0,0,0,0,0};
        for (int j = 0; j < 256; j++) cnt[xsTab[j]]++;
        int run[8] = {0,0,0,0,0,0,0,0};
        int myGrp = -1, myRole = -1, ovK = -1, ovCount = 0;
        for (int j = 0; j < 256; j++) {
            int xv = xsTab[j];
            int r = run[xv]++;
            if (r < 32) {
                if (j == (int)blockIdx.x) { myGrp = xv; myRole = r; }
            } else {
                if (j == (int)blockIdx.x) ovK = ovCount;
                ovCount++;
            }
        }
        if (myGrp < 0) {
            int k2 = 0; bool done = false;
            for (int gg = 0; gg < 8 && !done; gg++)
                for (int rr = cnt[gg]; rr < 32 && !done; rr++) {
                    if (k2 == ovK) { myGrp = gg; myRole = rr; done = true; }
                    k2++;
                }
        }
        if (myGrp < 0) { myGrp = blockIdx.x & 7; myRole = blockIdx.x >> 3; }  // paranoia
        asn[0] = myGrp;
        asn[1] = myRole;
        asn[2] = (cnt[myGrp] >= 32) ? 1 : 0;   // all-local group -> fast eligible
    }
    __syncthreads();
    const int g = asn[0];
    const int loc = asn[1];
    const int fastInit = asn[2];

    if (loc < 16)
        run_layer<0, 4, 10, 328>(g, loc, threadIdx.x, fastInit, x, flags, bias,
                                 h1r, h2r, h1f, h2f, wf1, hOut, sA, sB, red, &fastMode);
    else
        run_layer<1, 6, 16, 520>(g, loc - 16, threadIdx.x, fastInit, x, flags, bias,
                                 h1r, h2r, h1f, h2f, wf2, hOut, sA, sB, red, &fastMode);
}

// ---------------- head MLP ----------------

__global__ void head_mlp(const float* hOut, const float* W1, const float* b1,
                         const float* W2, const float* b2, const float* W3, const float* b3,
                         float* out)
{
    __shared__ float h[256];
    __shared__ float a1[128];
    __shared__ float a2[64];
    int b = blockIdx.x, j = threadIdx.x;
    for (int k = j; k < 256; k += 128)
        h[k] = ld_cg_f32(hOut + (size_t)b * HID + k);
    __syncthreads();
    float s = b1[j];
    for (int k = 0; k < 256; k++) s += W1[j * 256 + k] * h[k];
    a1[j] = fmaxf(s, 0.f);
    __syncthreads();
    if (j < 64) {
        float s2 = b2[j];
        for (int k = 0; k < 128; k++) s2 += W2[j * 128 + k] * a1[k];
        a2[j] = fmaxf(s2, 0.f);
    }
    __syncthreads();
    if (j == 0) {
        float s3 = b3[0];
        for (int k = 0; k < 64; k++) s3 += W3[k] * a2[k];
        out[b] = s3;
    }
}

// ---------------- launch ----------------

extern "C" void kernel_launch(void* const* d_in, const int* in_sizes, int n_in,
                              void* d_out, int out_size, void* d_ws, size_t ws_size,
                              hipStream_t stream)
{
    const float* x    = (const float*)d_in[0];
    const float* Wxh1 = (const float*)d_in[1];
    const float* bxh1 = (const float*)d_in[2];
    const float* Whh1 = (const float*)d_in[3];
    const float* bhh1 = (const float*)d_in[4];
    const float* Wxh2 = (const float*)d_in[5];
    const float* bxh2 = (const float*)d_in[6];
    const float* Whh2 = (const float*)d_in[7];
    const float* bhh2 = (const float*)d_in[8];
    const float* W1   = (const float*)d_in[9];
    const float* b1   = (const float*)d_in[10];
    const float* W2   = (const float*)d_in[11];
    const float* b2   = (const float*)d_in[12];
    const float* W3   = (const float*)d_in[13];
    const float* b3   = (const float*)d_in[14];

    char* w = (char*)d_ws;
    int*      flags = (int*)(w + OFF_FLAGS);
    float*    bias  = (float*)(w + OFF_BIAS);
    unsigned* h1r   = (unsigned*)(w + OFF_H1R);
    unsigned* h2r   = (unsigned*)(w + OFF_H2R);
    unsigned* h1f   = (unsigned*)(w + OFF_H1F);
    unsigned* h2f   = (unsigned*)(w + OFF_H2F);
    ushort_t* wf1   = (ushort_t*)(w + OFF_WF1);
    ushort_t* wf2   = (ushort_t*)(w + OFF_WF2);
    float*    hOut  = (float*)(w + OFF_HOUT);

    prep_misc<<<(6144 + 4 * RING_DW + 255) / 256, 256, 0, stream>>>(
        bxh1, bhh1, bxh2, bhh2, bias, flags, h1r);
    prep_wf<<<((WF1_FRAGS + WF2_FRAGS) * 512 + 255) / 256, 256, 0, stream>>>(
        Wxh1, Whh1, Wxh2, Whh2, wf1, wf2);

    const float* xp = x;
    void* args[] = { (void*)&xp, (void*)&flags, (void*)&bias,
                     (void*)&h1r, (void*)&h2r, (void*)&h1f, (void*)&h2f,
                     (void*)&wf1, (void*)&wf2, (void*)&hOut };
    hipLaunchCooperativeKernel((void*)recur, dim3(256), dim3(512), args, 0, stream);

    head_mlp<<<NBATCH, 128, 0, stream>>>(hOut, W1, b1, W2, b2, W3, b3, (float*)d_out);
}

// Round 11
// 1620.824 us; speedup vs baseline: 1.3729x; 1.3729x over previous
//
#include <hip/hip_runtime.h>
#include <stdint.h>

typedef unsigned short ushort_t;
typedef __attribute__((ext_vector_type(8))) short short8;
typedef __attribute__((ext_vector_type(4))) float float4v;
typedef __attribute__((ext_vector_type(4))) int int4v;

#define TSTEPS 512
#define NBATCH 128
#define HID 256
#define NIN 64
#define RB 32           // ring depth (steps); gen bit flips every RB steps
#define NBHID (NBATCH*HID)
#define RING_DW (RB*NBHID)

// workspace layout (bytes) — ring: u32 per element = (lo_bf16<<16) | tagged_hi
// flags (lazy backpressure only): padded, one int per 64B line
#define OFF_FLAGS   0u                             // 4096 ints = 16KB
#define OFF_BIAS    16384u
#define OFF_H1R     32768u
#define RING_BYTES  (RB*(unsigned)NBATCH*HID*4u)   // 4,194,304 per ring
#define OFF_H2R     (OFF_H1R + RING_BYTES)
#define OFF_WF1     (OFF_H2R + RING_BYTES)
#define WF1_FRAGS   (16*8*4*4)                     // 2048 fragments of 1KB
#define OFF_WF2     (OFF_WF1 + WF1_FRAGS*1024u)
#define WF2_FRAGS   (16*8*6*4)                     // 3072
#define OFF_HOUT    (OFF_WF2 + WF2_FRAGS*1024u)    // 128*256 fp32 = 128KB

// Protocol = R8 EXACTLY (verified 1787us, absmax 0.0):
//  - ring u32 = (lo<<16) | hi, hi's LSB = gen(t) = (t>>5)&1; lo computed vs
//    the TAGGED hi at full RNE precision (absmax 0.0, verified R4/R8/R9).
//  - producer: tagged stores, NO drain, NO flag. Sentinel = (row15,col15)
//    word of each slice (stored by wave7 lane63 in this version).
//  - consumer wave1 polls sentinels; bulk stage load validates every word's
//    tag (rare retry = safety net for store-order skew).
//  - backpressure: lazy progress flags every 8 steps, slack 22 (< RB-8).
//  - rings prefilled 0x00000001: tag=1=gen(-1), value ~ 0.
// New vs R8 (the only change): reduction+cell parallelized 4-way — all 8
// waves dump acc TRANSPOSED (red2[r2][wv][nt][lane]); waves 4-7 each own one
// r2 slice: 32 conflict-free scalar loads + ONE scalar cell + ONE store.
// Cuts wave0's ~400-600cy serial tail (28 b128 loads + 4 serial cells) 4x.

__device__ __forceinline__ ushort_t bf16h(float f) {
    unsigned u = __float_as_uint(f);
    u += 0x7fffu + ((u >> 16) & 1u);
    return (ushort_t)(u >> 16);
}
__device__ __forceinline__ float bf16f(ushort_t h) {
    return __uint_as_float(((unsigned)h) << 16);
}
__device__ __forceinline__ unsigned genbit(int s) {   // valid for s >= -64
    return ((unsigned)(s + 64) >> 5) & 1u;
}

// ---- IC-coherent (device-scope) access helpers: sc0 sc1 ----

__device__ __forceinline__ int ld_cg_i32(const void* p) {
    int r;
    asm volatile("global_load_dword %0, %1, off sc0 sc1\n\ts_waitcnt vmcnt(0)"
                 : "=v"(r) : "v"(p) : "memory");
    return r;
}
__device__ __forceinline__ float ld_cg_f32(const void* p) {
    float r;
    asm volatile("global_load_dword %0, %1, off sc0 sc1\n\ts_waitcnt vmcnt(0)"
                 : "=v"(r) : "v"(p) : "memory");
    return r;
}
// 8 consecutive u32 (32B), waited
__device__ __forceinline__ void ld2x4(int4v& a, int4v& b, const void* p) {
    asm volatile("global_load_dwordx4 %0, %2, off sc0 sc1\n\t"
                 "global_load_dwordx4 %1, %2, off offset:16 sc0 sc1\n\t"
                 "s_waitcnt vmcnt(0)"
                 : "=&v"(a), "=&v"(b) : "v"(p) : "memory");
}
// 8 u32 from each of two base pointers, one wait
__device__ __forceinline__ void ld4x4(int4v& a, int4v& b, int4v& c, int4v& d,
                                      const void* p, const void* q) {
    asm volatile("global_load_dwordx4 %0, %4, off sc0 sc1\n\t"
                 "global_load_dwordx4 %1, %4, off offset:16 sc0 sc1\n\t"
                 "global_load_dwordx4 %2, %5, off sc0 sc1\n\t"
                 "global_load_dwordx4 %3, %5, off offset:16 sc0 sc1\n\t"
                 "s_waitcnt vmcnt(0)"
                 : "=&v"(a), "=&v"(b), "=&v"(c), "=&v"(d)
                 : "v"(p), "v"(q) : "memory");
}
__device__ __forceinline__ void st_cg_u32(void* p, unsigned v) {
    asm volatile("global_store_dword %0, %1, off sc0 sc1" :: "v"(p), "v"(v) : "memory");
}
__device__ __forceinline__ void st_cg_i32(int* p, int v) {
    asm volatile("global_store_dword %0, %1, off sc0 sc1" :: "v"(p), "v"(v) : "memory");
}
__device__ __forceinline__ void st_cg_f32(void* p, float v) {
    asm volatile("global_store_dword %0, %1, off sc0 sc1" :: "v"(p), "v"(v) : "memory");
}

// all 8 u32 LSBs (the hi-plane tags) equal gw (0 or 1)?
__device__ __forceinline__ bool tag8(int4v a, int4v b, unsigned gw) {
    unsigned x = ((unsigned)a[0] ^ gw) | ((unsigned)a[1] ^ gw) |
                 ((unsigned)a[2] ^ gw) | ((unsigned)a[3] ^ gw) |
                 ((unsigned)b[0] ^ gw) | ((unsigned)b[1] ^ gw) |
                 ((unsigned)b[2] ^ gw) | ((unsigned)b[3] ^ gw);
    return (x & 1u) == 0u;
}

// extract 8 low u16 (hi plane) / 8 high u16 (lo plane) from 8 packed u32
__device__ __forceinline__ int4v ext_hi8(int4v a, int4v b) {
    int4v r;
    r[0] = (int)__builtin_amdgcn_perm((unsigned)a[1], (unsigned)a[0], 0x05040100u);
    r[1] = (int)__builtin_amdgcn_perm((unsigned)a[3], (unsigned)a[2], 0x05040100u);
    r[2] = (int)__builtin_amdgcn_perm((unsigned)b[1], (unsigned)b[0], 0x05040100u);
    r[3] = (int)__builtin_amdgcn_perm((unsigned)b[3], (unsigned)b[2], 0x05040100u);
    return r;
}
__device__ __forceinline__ int4v ext_lo8(int4v a, int4v b) {
    int4v r;
    r[0] = (int)__builtin_amdgcn_perm((unsigned)a[1], (unsigned)a[0], 0x07060302u);
    r[1] = (int)__builtin_amdgcn_perm((unsigned)a[3], (unsigned)a[2], 0x07060302u);
    r[2] = (int)__builtin_amdgcn_perm((unsigned)b[1], (unsigned)b[0], 0x07060302u);
    r[3] = (int)__builtin_amdgcn_perm((unsigned)b[3], (unsigned)b[2], 0x07060302u);
    return r;
}

// ---------------- prep kernels ----------------

__global__ void prep_misc(const float* bxh1, const float* bhh1,
                          const float* bxh2, const float* bhh2,
                          float* bias, int* flags, unsigned* ring_all)
{
    int n = blockIdx.x * blockDim.x + threadIdx.x;
    if (n < 1024)       bias[n] = bxh1[n] + bhh1[n];
    else if (n < 2048)  bias[n] = bxh2[n - 1024] + bhh2[n - 1024];
    else if (n < 6144)  flags[n - 2048] = 0;        // 4096 padded flag ints
    else {
        unsigned d = n - 6144;
        if (d < 2u * RING_DW)
            ring_all[d] = 0x00000001u;   // tag = gen(-1) = 1, value ~ 0
    }
}

// Build MFMA B-fragments (hi/lo split weights) in exact consumption order:
// fragment id = ((slice*8 + wave)*F + i)*4 + ntile ; each fragment = [lane][8] bf16.
__global__ void prep_wf(const float* Wxh1, const float* Whh1,
                        const float* Wxh2, const float* Whh2,
                        ushort_t* wf1, ushort_t* wf2)
{
    int n = blockIdx.x * blockDim.x + threadIdx.x;
    const int L1E = WF1_FRAGS * 512;
    const int L2E = WF2_FRAGS * 512;
    if (n >= L1E + L2E) return;
    int layer = (n >= L1E) ? 1 : 0;
    int e = layer ? (n - L1E) : n;
    int el = e & 511;
    int f  = e >> 9;
    int lane = el >> 3, j = el & 7;
    int nt = f & 3;
    int rem = f >> 2;
    int i, wv, slice, F, S;
    if (!layer) { F = 4; S = 10; i = rem & 3; wv = (rem >> 2) & 7; slice = rem >> 5; }
    else        { F = 6; S = 16; i = rem % 6; int r2 = rem / 6; wv = r2 & 7; slice = r2 >> 3; }
    int fg = wv * F + i;
    int col = lane & 15;
    int row = nt * 256 + slice * 16 + col;
    float val = 0.f;
    if (fg < 3 * S) {
        int sec = (fg < S) ? 0 : ((fg < 2 * S) ? 1 : 2);
        int ks = (fg - sec * S) * 32 + (lane >> 4) * 8 + j;
        float w;
        if (!layer) w = (ks < 256) ? Whh1[row * 256 + ks] : Wxh1[row * 64 + (ks - 256)];
        else        w = (ks < 256) ? Wxh2[row * 256 + ks] : Whh2[row * 256 + (ks - 256)];
        ushort_t hi = bf16h(w);
        val = (sec < 2) ? bf16f(hi) : (w - bf16f(hi));
    }
    (layer ? wf2 : wf1)[e] = bf16h(val);
}

// ---------------- recurrent kernel ----------------
// grid = 256 WGs x 512 threads. blockIdx%8 = batch group, blockIdx/8: [0,16)
// layer1 slice, [16,32) layer2 slice.
// Per step: {w2-3: x->LDS | w1: sentinel polls + backpressure} -> barrier ->
// cooperative tag-validated stage -> barrier -> MFMA -> ALL waves dump acc
// transposed -> barrier -> waves4-7: per-r2 sum + scalar cell + 1 tagged store.

template<int LAYER, int F, int S, int PITCH>
__device__ __forceinline__ void run_layer(
    int g, int slice, int tid, const float* __restrict__ x,
    int* flags, const float* bias,
    unsigned* h1r, unsigned* h2r, const ushort_t* wfrag, float* hOut,
    ushort_t* sA, ushort_t* sB, float (*red2)[8][4][64])
{
    const int wv = tid >> 6, lane = tid & 63;
    const int mrow = lane & 15, q = lane >> 4;
    int* f1 = flags + g * 256;                    // layer1 progress (stride 16)
    int* f2 = flags + 2048 + g * 256;             // layer2 progress
    int* myflag = flags + LAYER * 2048 + g * 256 + slice * 16;

    // persistent B fragments in VGPRs
    short8 bw[4][F];
    {
        const ushort_t* base = wfrag + (size_t)((slice * 8 + wv) * F) * 4 * 512;
        #pragma unroll
        for (int i = 0; i < F; i++)
            #pragma unroll
            for (int nt = 0; nt < 4; nt++)
                bw[nt][i] = *(const short8*)(base + (i * 4 + nt) * 512 + lane * 8);
    }

    float bs[4];
    #pragma unroll
    for (int nt = 0; nt < 4; nt++)
        bs[nt] = bias[LAYER * 1024 + nt * 256 + slice * 16 + mrow];

    // cell state: waves 4-7 only, one cell per lane (row = g*16+q*4+(wv-4))
    float cst = 0.f, mst = 0.f, nst = 0.f;

    const int sr = tid >> 5, k = tid & 31;  // staging: row sr, element chunk k*8
    const int row = g * 16 + sr;

    for (int t = 0; t < TSTEPS; t++) {
        // ---- x staging (layer1, waves 2-3; plain cached loads) ----
        if (LAYER == 0 && tid >= 128 && tid < 256) {
            int idx = tid - 128;          // 0..127
            int r = idx >> 3, o = idx & 7;
            const float* xsrc = x + ((size_t)(g * 16 + r) * TSTEPS + t) * NIN + o * 8;
            float4v x0 = *(const float4v*)xsrc;
            float4v x1 = *(const float4v*)(xsrc + 4);
            float xs[8] = {x0[0], x0[1], x0[2], x0[3], x1[0], x1[1], x1[2], x1[3]};
            union { ushort_t u[8]; int4v v4; } hiP, loP;
            #pragma unroll
            for (int z = 0; z < 8; z++) {
                ushort_t hi = bf16h(xs[z]);
                hiP.u[z] = hi;
                loP.u[z] = bf16h(xs[z] - bf16f(hi));
            }
            *(int4v*)(sA + r * PITCH + (32 + o) * 8) = hiP.v4;
            *(int4v*)(sB + r * PITCH + (32 + o) * 8) = loP.v4;
        }

        // ---- wave1: sentinel discovery + lazy backpressure (R8 verbatim) ----
        if (tid >= 64 && tid < 128) {
            int pl = tid - 64;
            if (pl < 16) {
                const unsigned* sp;
                unsigned want;
                if (LAYER == 0) {
                    sp = h1r + (size_t)((t - 1) & (RB - 1)) * NBHID
                             + (size_t)(g * 16 + 15) * HID + pl * 16 + 15;
                    want = genbit(t - 1);
                } else {
                    sp = h1r + (size_t)(t & (RB - 1)) * NBHID
                             + (size_t)(g * 16 + 15) * HID + pl * 16 + 15;
                    want = genbit(t);
                }
                while ((((unsigned)ld_cg_i32(sp)) & 1u) != want) { }
            } else if (pl < 32) {
                if (LAYER == 1) {
                    const unsigned* sp = h2r + (size_t)((t - 1) & (RB - 1)) * NBHID
                                             + (size_t)(g * 16 + 15) * HID + (pl - 16) * 16 + 15;
                    unsigned want = genbit(t - 1);
                    while ((((unsigned)ld_cg_i32(sp)) & 1u) != want) { }
                }
            } else if ((t & 7) == 0) {
                int thr = t - 22;
                const int* p = nullptr;
                if (LAYER == 0) {
                    if (pl < 48)      p = f1 + (pl - 32) * 16;
                    else              p = f2 + (pl - 48) * 16;
                } else {
                    if (pl < 48)      p = f2 + (pl - 32) * 16;
                }
                if (p)
                    while (ld_cg_i32(p) < thr) { }
            }
        }
        __syncthreads();

        // ---- cooperative tag-validated stage: packed ring -> LDS ----
        {
            if (LAYER == 0) {
                const unsigned* base = h1r + ((size_t)((t - 1) & (RB - 1)) * NBATCH + row) * HID + k * 8;
                unsigned w = genbit(t - 1);
                int4v a, b;
                do { ld2x4(a, b, base); } while (!tag8(a, b, w));
                *(int4v*)(sA + sr * PITCH + k * 8) = ext_hi8(a, b);
                *(int4v*)(sB + sr * PITCH + k * 8) = ext_lo8(a, b);
            } else {
                const unsigned* b1 = h1r + ((size_t)(t & (RB - 1)) * NBATCH + row) * HID + k * 8;
                const unsigned* b2 = h2r + ((size_t)((t - 1) & (RB - 1)) * NBATCH + row) * HID + k * 8;
                unsigned w1 = genbit(t), w2 = genbit(t - 1);
                int4v a, b, c, d;
                do { ld4x4(a, b, c, d, b1, b2); } while (!(tag8(a, b, w1) && tag8(c, d, w2)));
                *(int4v*)(sA + sr * PITCH + k * 8)        = ext_hi8(a, b);
                *(int4v*)(sB + sr * PITCH + k * 8)        = ext_lo8(a, b);
                *(int4v*)(sA + sr * PITCH + (32 + k) * 8) = ext_hi8(c, d);
                *(int4v*)(sB + sr * PITCH + (32 + k) * 8) = ext_lo8(c, d);
            }
        }
        __syncthreads();

        // ---- progress publish (lazy backpressure input; off critical path) ----
        if (tid == 256 && (t & 7) == 0)
            st_cg_i32(myflag, t);

        // ---- MFMA: this wave's K-chunks across the 4 gate N-tiles ----
        float4v acc[4] = {};
        #pragma unroll
        for (int i = 0; i < F; i++) {
            const int fg = wv * F + i;
            short8 a;
            if (fg < 3 * S) {
                int sec = (fg >= S && fg < 2 * S) ? 1 : 0;
                int ks = ((fg < S) ? fg : ((fg < 2 * S) ? fg - S : fg - 2 * S)) * 32;
                const ushort_t* ap = (sec ? sB : sA) + mrow * PITCH + ks + q * 8;
                a = *(const short8*)ap;
            } else {
                a = (short8){0,0,0,0,0,0,0,0};
            }
            #pragma unroll
            for (int nt = 0; nt < 4; nt++)
                acc[nt] = __builtin_amdgcn_mfma_f32_16x16x32_bf16(a, bw[nt][i], acc[nt], 0, 0, 0);
        }

        // ---- ALL waves dump acc transposed (conflict-free scalar stores) ----
        #pragma unroll
        for (int nt = 0; nt < 4; nt++)
            #pragma unroll
            for (int r2 = 0; r2 < 4; r2++)
                red2[r2][wv][nt][lane] = acc[nt][r2];
        __syncthreads();

        // ---- waves 4-7: per-r2 sum + scalar cell + ONE tagged store ----
        if (wv >= 4) {
            const int r2 = wv - 4;
            float gate[4];
            #pragma unroll
            for (int nt = 0; nt < 4; nt++) {
                float s = red2[r2][0][nt][lane];
                #pragma unroll
                for (int w = 1; w < 8; w++) s += red2[r2][w][nt][lane];
                gate[nt] = s + bs[nt];
            }
            float ig  = gate[0];
            float fgt = gate[1];
            float zg  = gate[2];
            float og  = gate[3];
            float zc = fminf(fmaxf(zg, -15.f), 15.f);
            float e2 = __expf(2.f * zc);
            float zt = (e2 - 1.f) / (e2 + 1.f);
            float ot = 1.f / (1.f + __expf(-og));
            float mt = fmaxf(fgt + mst, ig);
            float it = __expf(ig - mt);
            float ft = __expf(fgt + mst - mt);
            cst = ft * cst + it * zt;
            nst = ft * nst + it;
            mst = mt;
            float h = ot * (cst / nst);
            unsigned gw = genbit(t);
            // tagged hi (LSB = gen); lo computed vs tagged hi at full RNE
            ushort_t hi = (ushort_t)(((unsigned)bf16h(h) & 0xFFFEu) | gw);
            float rem = h - bf16f(hi);
            ushort_t lo = bf16h(rem);
            unsigned word = ((unsigned)lo << 16) | (unsigned)hi;
            unsigned* base = (LAYER ? h2r : h1r) + (size_t)(t & (RB - 1)) * NBHID;
            int orow = g * 16 + q * 4 + r2;
            int col = slice * 16 + mrow;
            st_cg_u32(base + (size_t)orow * HID + col, word);
            if (LAYER == 1 && t == TSTEPS - 1)
                st_cg_f32(hOut + (size_t)orow * HID + col, h);
            // sentinel (row g*16+15, col slice*16+15) = wave7 lane63's word.
        }
    }
}

__global__ __launch_bounds__(512, 2) void recur(
    const float* __restrict__ x,
    int* flags, const float* bias,
    unsigned* h1r, unsigned* h2r, const ushort_t* wf1, const ushort_t* wf2, float* hOut)
{
    __shared__ alignas(16) ushort_t sA[16 * 520];
    __shared__ alignas(16) ushort_t sB[16 * 520];
    __shared__ float red2[4][8][4][64];
    int g = blockIdx.x & 7;
    int loc = blockIdx.x >> 3;
    if (loc < 16)
        run_layer<0, 4, 10, 328>(g, loc, threadIdx.x, x, flags, bias, h1r, h2r, wf1, hOut, sA, sB, red2);
    else
        run_layer<1, 6, 16, 520>(g, loc - 16, threadIdx.x, x, flags, bias, h1r, h2r, wf2, hOut, sA, sB, red2);
}

// ---------------- head MLP ----------------

__global__ void head_mlp(const float* hOut, const float* W1, const float* b1,
                         const float* W2, const float* b2, const float* W3, const float* b3,
                         float* out)
{
    __shared__ float h[256];
    __shared__ float a1[128];
    __shared__ float a2[64];
    int b = blockIdx.x, j = threadIdx.x;
    for (int k = j; k < 256; k += 128)
        h[k] = ld_cg_f32(hOut + (size_t)b * HID + k);
    __syncthreads();
    float s = b1[j];
    for (int k = 0; k < 256; k++) s += W1[j * 256 + k] * h[k];
    a1[j] = fmaxf(s, 0.f);
    __syncthreads();
    if (j < 64) {
        float s2 = b2[j];
        for (int k = 0; k < 128; k++) s2 += W2[j * 128 + k] * a1[k];
        a2[j] = fmaxf(s2, 0.f);
    }
    __syncthreads();
    if (j == 0) {
        float s3 = b3[0];
        for (int k = 0; k < 64; k++) s3 += W3[k] * a2[k];
        out[b] = s3;
    }
}

// ---------------- launch ----------------

extern "C" void kernel_launch(void* const* d_in, const int* in_sizes, int n_in,
                              void* d_out, int out_size, void* d_ws, size_t ws_size,
                              hipStream_t stream)
{
    const float* x    = (const float*)d_in[0];
    const float* Wxh1 = (const float*)d_in[1];
    const float* bxh1 = (const float*)d_in[2];
    const float* Whh1 = (const float*)d_in[3];
    const float* bhh1 = (const float*)d_in[4];
    const float* Wxh2 = (const float*)d_in[5];
    const float* bxh2 = (const float*)d_in[6];
    const float* Whh2 = (const float*)d_in[7];
    const float* bhh2 = (const float*)d_in[8];
    const float* W1   = (const float*)d_in[9];
    const float* b1   = (const float*)d_in[10];
    const float* W2   = (const float*)d_in[11];
    const float* b2   = (const float*)d_in[12];
    const float* W3   = (const float*)d_in[13];
    const float* b3   = (const float*)d_in[14];

    char* w = (char*)d_ws;
    int*      flags = (int*)(w + OFF_FLAGS);
    float*    bias  = (float*)(w + OFF_BIAS);
    unsigned* h1r   = (unsigned*)(w + OFF_H1R);
    unsigned* h2r   = (unsigned*)(w + OFF_H2R);
    ushort_t* wf1   = (ushort_t*)(w + OFF_WF1);
    ushort_t* wf2   = (ushort_t*)(w + OFF_WF2);
    float*    hOut  = (float*)(w + OFF_HOUT);

    prep_misc<<<(6144 + 2 * RING_DW + 255) / 256, 256, 0, stream>>>(
        bxh1, bhh1, bxh2, bhh2, bias, flags, h1r);
    prep_wf<<<((WF1_FRAGS + WF2_FRAGS) * 512 + 255) / 256, 256, 0, stream>>>(
        Wxh1, Whh1, Wxh2, Whh2, wf1, wf2);

    const float* xp = x;
    void* args[] = { (void*)&xp, (void*)&flags, (void*)&bias,
                     (void*)&h1r, (void*)&h2r, (void*)&wf1, (void*)&wf2, (void*)&hOut };
    hipLaunchCooperativeKernel((void*)recur, dim3(256), dim3(512), args, 0, stream);

    head_mlp<<<NBATCH, 128, 0, stream>>>(hOut, W1, b1, W2, b2, W3, b3, (float*)d_out);
}